// Round 10
// baseline (259.559 us; speedup 1.0000x reference)
//
#include <hip/hip_runtime.h>
#include <math.h>

#define B_SZ 2
#define T_LEN 1024
#define D_MODEL 1024
#define D_STATE 16
#define D_INNER 2048
#define DT_RANK 64
#define NTOK (B_SZ * T_LEN)               // 2048 tokens
#define XPROJ_OUT 96
#define XPROJ_LD 128                      // padded leading dim for dbc
#define NCHUNK 32
#define CHUNK_L (T_LEN / NCHUNK)          // 32
#define NSPLIT 32                         // split-K for x_proj (K-slab 64)

typedef __attribute__((ext_vector_type(8))) short bf16x8;
typedef __attribute__((ext_vector_type(4))) float f32x4;

__device__ __forceinline__ float sigmoidf_(float x) { return 1.f / (1.f + __expf(-x)); }

__device__ __forceinline__ unsigned f2bf_u(float f) {  // RNE f32->bf16 bits
    unsigned u = __float_as_uint(f);
    return (u + 0x7FFFu + ((u >> 16) & 1u)) >> 16;
}
__device__ __forceinline__ float bf2f(unsigned short u) {
    return __uint_as_float((unsigned)u << 16);
}

__device__ __forceinline__ void gload_lds16(const void* g, void* l) {
    __builtin_amdgcn_global_load_lds((const __attribute__((address_space(1))) unsigned*)g,
                                     (__attribute__((address_space(3))) unsigned*)l,
                                     16, 0, 0);
}

// ---------------- fused prep: RMSNorm + all weight casts, one launch ----------------
__global__ __launch_bounds__(256) void k_prep(const float* __restrict__ x,
                                              const float* __restrict__ norm_w,
                                              const float* __restrict__ w_in,
                                              const float* __restrict__ w_out,
                                              const float* __restrict__ w_x,
                                              const float* __restrict__ w_dt,
                                              unsigned short* __restrict__ xn,
                                              unsigned* __restrict__ wib,
                                              unsigned* __restrict__ wob,
                                              unsigned* __restrict__ wxb,
                                              unsigned* __restrict__ wdtb) {
    __shared__ float red[4];
    int blk = blockIdx.x;
    if (blk < 2048) {  // RMSNorm row
        const float* xr = x + (size_t)blk * D_MODEL;
        int i = threadIdx.x * 4;
        float4 xv = *(const float4*)(xr + i);
        float s = xv.x * xv.x + xv.y * xv.y + xv.z * xv.z + xv.w * xv.w;
#pragma unroll
        for (int m = 1; m <= 32; m <<= 1) s += __shfl_xor(s, m);
        if ((threadIdx.x & 63) == 0) red[threadIdx.x >> 6] = s;
        __syncthreads();
        float tot = red[0] + red[1] + red[2] + red[3];
        float scale = rsqrtf(tot * (1.f / D_MODEL) + 1.1920929e-07f);
        float4 wv = *(const float4*)(norm_w + i);
        uint2 o;
        o.x = f2bf_u(xv.x * scale * wv.x) | (f2bf_u(xv.y * scale * wv.y) << 16);
        o.y = f2bf_u(xv.z * scale * wv.z) | (f2bf_u(xv.w * scale * wv.w) << 16);
        *(uint2*)(xn + (size_t)blk * D_MODEL + i) = o;
        return;
    }
    blk -= 2048;
    const float* src;
    unsigned* dst;
    int lidx;  // index in units of 8 elems
    if (blk < 2048) {
        src = w_in; dst = wib; lidx = blk * 256 + threadIdx.x;
    } else if (blk < 3072) {
        src = w_out; dst = wob; lidx = (blk - 2048) * 256 + threadIdx.x;
    } else if (blk < 3200) {
        dst = wxb; lidx = (blk - 3072) * 256 + threadIdx.x;
        if (lidx * 8 >= 96 * 2048) {  // pad rows 96..127 with zeros
            uint4 z = {0, 0, 0, 0};
            ((uint4*)dst)[lidx] = z;
            return;
        }
        src = w_x;
    } else {
        src = w_dt; dst = wdtb; lidx = (blk - 3200) * 256 + threadIdx.x;
    }
    float4 a = ((const float4*)src)[lidx * 2];
    float4 b = ((const float4*)src)[lidx * 2 + 1];
    uint4 o;
    o.x = f2bf_u(a.x) | (f2bf_u(a.y) << 16);
    o.y = f2bf_u(a.z) | (f2bf_u(a.w) << 16);
    o.z = f2bf_u(b.x) | (f2bf_u(b.y) << 16);
    o.w = f2bf_u(b.z) | (f2bf_u(b.w) << 16);
    ((uint4*)dst)[lidx] = o;
}

// ---------------- bf16 MFMA GEMM, BM=128, BK=64: C = A(MxK) * B(NxK)^T ----------------
// EPI: 1 = softplus(v + res[col]) bf16 out; 3 = bf16 out, silu when n0 >= D_INNER.
// 3 blocks/CU: LDS 32KB -> 96KB/CU, VGPR cap ~170 (no spill: acc 64 + frags 32).
template <int BN, int CW, int EPI>
__global__ __launch_bounds__(256, 3) void gemm_bf16(const unsigned short* __restrict__ A,
                                                    const unsigned short* __restrict__ B,
                                                    void* __restrict__ Cv, int ldc, int K,
                                                    const float* __restrict__ res) {
    constexpr int RW = 4 / CW;
    constexpr int MI = (128 / RW) / 16;
    constexpr int NJ = (BN / CW) / 16;
    __shared__ __align__(16) unsigned short As[128 * 64];
    __shared__ __align__(16) unsigned short Bs[BN * 64];
    int tid = threadIdx.x;
    int lane = tid & 63, wv = tid >> 6;
    int wr = wv / CW, wc = wv % CW;
    int lm = lane & 15, q = lane >> 4;
    int m0 = blockIdx.x * 128, n0 = blockIdx.y * BN;
    f32x4 acc[MI][NJ] = {};
    for (int k0 = 0; k0 < K; k0 += 64) {
#pragma unroll
        for (int it = 0; it < 4; ++it) {
            int chunk = it * 256 + tid;
            const unsigned short* g = A + (size_t)(m0 + (chunk >> 3)) * K + k0 + (chunk & 7) * 8;
            char* l = (char*)As + (it * 256 + wv * 64) * 16 + lane * 16;
            gload_lds16(g, l);
        }
#pragma unroll
        for (int it = 0; it < BN / 32; ++it) {
            int chunk = it * 256 + tid;
            const unsigned short* g = B + (size_t)(n0 + (chunk >> 3)) * K + k0 + (chunk & 7) * 8;
            char* l = (char*)Bs + (it * 256 + wv * 64) * 16 + lane * 16;
            gload_lds16(g, l);
        }
        __syncthreads();
#pragma unroll
        for (int h = 0; h < 2; ++h) {
            bf16x8 af[MI], bfr[NJ];
#pragma unroll
            for (int i = 0; i < MI; ++i)
                af[i] = *(const bf16x8*)(As + (wr * MI * 16 + i * 16 + lm) * 64 + h * 32 + q * 8);
#pragma unroll
            for (int j = 0; j < NJ; ++j)
                bfr[j] = *(const bf16x8*)(Bs + (wc * NJ * 16 + j * 16 + lm) * 64 + h * 32 + q * 8);
#pragma unroll
            for (int i = 0; i < MI; ++i)
#pragma unroll
                for (int j = 0; j < NJ; ++j)
                    acc[i][j] = __builtin_amdgcn_mfma_f32_16x16x32_bf16(af[i], bfr[j], acc[i][j], 0, 0, 0);
        }
        __syncthreads();
    }
#pragma unroll
    for (int i = 0; i < MI; ++i) {
#pragma unroll
        for (int j = 0; j < NJ; ++j) {
#pragma unroll
            for (int r = 0; r < 4; ++r) {
                int row = m0 + wr * MI * 16 + i * 16 + q * 4 + r;
                int col = n0 + wc * NJ * 16 + j * 16 + lm;
                float v = acc[i][j][r];
                if (EPI == 1) {
                    v += res[col];
                    v = (v > 20.f) ? v : log1pf(__expf(v));
                    ((unsigned short*)Cv)[(size_t)row * ldc + col] = (unsigned short)f2bf_u(v);
                } else {  // EPI == 3
                    if (n0 >= D_INNER) v = v * sigmoidf_(v);  // fused silu(z)
                    ((unsigned short*)Cv)[(size_t)row * ldc + col] = (unsigned short)f2bf_u(v);
                }
            }
        }
    }
}

// ---------------- 64x64-tile bf16 MFMA GEMM (out_proj): C = A*B^T + res, f32 out ----------------
// 4 waves in 2x2; wave tile 32x32. 4 blocks/CU (LDS 16KB, VGPR cap 128).
__global__ __launch_bounds__(256, 4) void gemm_sq64(const unsigned short* __restrict__ A,
                                                    const unsigned short* __restrict__ B,
                                                    float* __restrict__ C, int ldc, int K,
                                                    const float* __restrict__ res) {
    __shared__ __align__(16) unsigned short As[64 * 64];
    __shared__ __align__(16) unsigned short Bs[64 * 64];
    int tid = threadIdx.x;
    int lane = tid & 63, wv = tid >> 6;
    int wr = wv >> 1, wc = wv & 1;
    int lm = lane & 15, q = lane >> 4;
    int m0 = blockIdx.x * 64, n0 = blockIdx.y * 64;
    f32x4 acc[2][2] = {};
    for (int k0 = 0; k0 < K; k0 += 64) {
#pragma unroll
        for (int it = 0; it < 2; ++it) {
            int chunk = it * 256 + tid;
            const unsigned short* g = A + (size_t)(m0 + (chunk >> 3)) * K + k0 + (chunk & 7) * 8;
            char* l = (char*)As + (it * 256 + wv * 64) * 16 + lane * 16;
            gload_lds16(g, l);
        }
#pragma unroll
        for (int it = 0; it < 2; ++it) {
            int chunk = it * 256 + tid;
            const unsigned short* g = B + (size_t)(n0 + (chunk >> 3)) * K + k0 + (chunk & 7) * 8;
            char* l = (char*)Bs + (it * 256 + wv * 64) * 16 + lane * 16;
            gload_lds16(g, l);
        }
        __syncthreads();
#pragma unroll
        for (int h = 0; h < 2; ++h) {
            bf16x8 af[2], bfr[2];
#pragma unroll
            for (int i = 0; i < 2; ++i)
                af[i] = *(const bf16x8*)(As + (wr * 32 + i * 16 + lm) * 64 + h * 32 + q * 8);
#pragma unroll
            for (int j = 0; j < 2; ++j)
                bfr[j] = *(const bf16x8*)(Bs + (wc * 32 + j * 16 + lm) * 64 + h * 32 + q * 8);
#pragma unroll
            for (int i = 0; i < 2; ++i)
#pragma unroll
                for (int j = 0; j < 2; ++j)
                    acc[i][j] = __builtin_amdgcn_mfma_f32_16x16x32_bf16(af[i], bfr[j], acc[i][j], 0, 0, 0);
        }
        __syncthreads();
    }
#pragma unroll
    for (int i = 0; i < 2; ++i)
#pragma unroll
        for (int j = 0; j < 2; ++j)
#pragma unroll
            for (int r = 0; r < 4; ++r) {
                int row = m0 + wr * 32 + i * 16 + q * 4 + r;
                int col = n0 + wc * 32 + j * 16 + lm;
                C[(size_t)row * ldc + col] = acc[i][j][r] + res[(size_t)row * ldc + col];
            }
}

// ---------------- x_proj split-K MFMA GEMM (K-slab 64, single stage) -> bf16 partials ----------------
__global__ __launch_bounds__(256, 3) void xproj_gemm(const unsigned short* __restrict__ A,
                                                     const unsigned short* __restrict__ B,
                                                     unsigned short* __restrict__ part) {
    constexpr int MI = 4, NJ = 4;
    __shared__ __align__(16) unsigned short As[128 * 64];
    __shared__ __align__(16) unsigned short Bs[128 * 64];
    int tid = threadIdx.x;
    int lane = tid & 63, wv = tid >> 6;
    int wr = wv >> 1, wc = wv & 1;
    int lm = lane & 15, q = lane >> 4;
    int m0 = blockIdx.x * 128;
    int k0 = blockIdx.y * 64;
    f32x4 acc[MI][NJ] = {};
#pragma unroll
    for (int it = 0; it < 4; ++it) {
        int chunk = it * 256 + tid;
        const unsigned short* g = A + (size_t)(m0 + (chunk >> 3)) * D_INNER + k0 + (chunk & 7) * 8;
        char* l = (char*)As + (it * 256 + wv * 64) * 16 + lane * 16;
        gload_lds16(g, l);
    }
#pragma unroll
    for (int it = 0; it < 4; ++it) {
        int chunk = it * 256 + tid;
        const unsigned short* g = B + (size_t)(chunk >> 3) * D_INNER + k0 + (chunk & 7) * 8;
        char* l = (char*)Bs + (it * 256 + wv * 64) * 16 + lane * 16;
        gload_lds16(g, l);
    }
    __syncthreads();
#pragma unroll
    for (int h = 0; h < 2; ++h) {
        bf16x8 af[MI], bfr[NJ];
#pragma unroll
        for (int i = 0; i < MI; ++i)
            af[i] = *(const bf16x8*)(As + (wr * 64 + i * 16 + lm) * 64 + h * 32 + q * 8);
#pragma unroll
        for (int j = 0; j < NJ; ++j)
            bfr[j] = *(const bf16x8*)(Bs + (wc * 64 + j * 16 + lm) * 64 + h * 32 + q * 8);
#pragma unroll
        for (int i = 0; i < MI; ++i)
#pragma unroll
            for (int j = 0; j < NJ; ++j)
                acc[i][j] = __builtin_amdgcn_mfma_f32_16x16x32_bf16(af[i], bfr[j], acc[i][j], 0, 0, 0);
    }
    unsigned short* dst = part + (size_t)blockIdx.y * (NTOK * XPROJ_LD);
#pragma unroll
    for (int i = 0; i < MI; ++i)
#pragma unroll
        for (int j = 0; j < NJ; ++j)
#pragma unroll
            for (int r = 0; r < 4; ++r) {
                int row = m0 + wr * 64 + i * 16 + q * 4 + r;
                int col = wc * 64 + j * 16 + lm;
                dst[(size_t)row * XPROJ_LD + col] = (unsigned short)f2bf_u(acc[i][j][r]);
            }
}

// ---------------- reduce split-K partials (4 elems/thread); emit dbc f32 + dt_raw bf16 ----------------
__global__ __launch_bounds__(256) void k_xred(const unsigned short* __restrict__ part,
                                              float* __restrict__ dbc,
                                              unsigned short* __restrict__ dtrawb) {
    int idx4 = blockIdx.x * 256 + threadIdx.x;  // unit of 4 elems; 0 .. 2048*128/4-1
    float s0 = 0.f, s1 = 0.f, s2 = 0.f, s3 = 0.f;
#pragma unroll
    for (int sp = 0; sp < NSPLIT; ++sp) {
        uint2 v = *(const uint2*)(part + (size_t)sp * (NTOK * XPROJ_LD) + idx4 * 4);
        s0 += __uint_as_float(v.x << 16);
        s1 += __uint_as_float(v.x & 0xFFFF0000u);
        s2 += __uint_as_float(v.y << 16);
        s3 += __uint_as_float(v.y & 0xFFFF0000u);
    }
    float4 sv = {s0, s1, s2, s3};
    *(float4*)(dbc + idx4 * 4) = sv;
    int col = (idx4 * 4) & (XPROJ_LD - 1);
    if (col < DT_RANK) {
        int row = (idx4 * 4) >> 7;
        uint2 o;
        o.x = f2bf_u(s0) | (f2bf_u(s1) << 16);
        o.y = f2bf_u(s2) | (f2bf_u(s3) << 16);
        *(uint2*)(dtrawb + (size_t)row * DT_RANK + col) = o;
    }
}

// ---------------- depthwise causal conv (k=4, bf16 in) + SiLU -> ub ----------------
__global__ __launch_bounds__(256) void k_conv(const unsigned short* __restrict__ xz,
                                              const float* __restrict__ cw,
                                              const float* __restrict__ cb,
                                              unsigned short* __restrict__ ub) {
    int idx = blockIdx.x * 256 + threadIdx.x;
    int c = idx & (D_INNER - 1);
    int t = (idx >> 11) & (T_LEN - 1);
    int b = idx >> 21;
    const unsigned short* xs = xz + (size_t)b * T_LEN * 2 * D_INNER + c;
    float4 wv = *(const float4*)(cw + c * 4);
    float s = cb[c];
    if (t >= 3) s = fmaf(bf2f(xs[(size_t)(t - 3) * 2 * D_INNER]), wv.x, s);
    if (t >= 2) s = fmaf(bf2f(xs[(size_t)(t - 2) * 2 * D_INNER]), wv.y, s);
    if (t >= 1) s = fmaf(bf2f(xs[(size_t)(t - 1) * 2 * D_INNER]), wv.z, s);
    s = fmaf(bf2f(xs[(size_t)t * 2 * D_INNER]), wv.w, s);
    float v = s * sigmoidf_(s);
    ub[idx] = (unsigned short)f2bf_u(v);
}

// ---------------- chunked selective scan, lane-per-channel ----------------
__global__ __launch_bounds__(256) void k_scan1(const unsigned short* __restrict__ delta,
                                               const unsigned short* __restrict__ ub,
                                               const float* __restrict__ dbc,
                                               const float* __restrict__ A_log,
                                               float* __restrict__ Pbuf,
                                               float* __restrict__ Hbuf) {
    int tid = threadIdx.x;
    int c = blockIdx.x * 256 + tid;
    int b = blockIdx.y >> 5, chunk = blockIdx.y & 31;
    int t0 = chunk * CHUNK_L;
    __shared__ float bc[CHUNK_L][32];  // [t][0:16]=B, [t][16:32]=C
    {
        int t = tid >> 3, col = (tid & 7) * 4;
        const float* src = dbc + ((size_t)b * T_LEN + t0 + t) * XPROJ_LD + DT_RANK + col;
        *(float4*)&bc[t][col] = *(const float4*)src;
    }
    __syncthreads();
    float A[16];
#pragma unroll
    for (int s4 = 0; s4 < 4; ++s4) {
        float4 av = *(const float4*)(A_log + (size_t)c * D_STATE + s4 * 4);
        A[s4 * 4 + 0] = -__expf(av.x);
        A[s4 * 4 + 1] = -__expf(av.y);
        A[s4 * 4 + 2] = -__expf(av.z);
        A[s4 * 4 + 3] = -__expf(av.w);
    }
    const unsigned short* dp = delta + ((size_t)b * T_LEN + t0) * D_INNER + c;
    const unsigned short* up = ub + ((size_t)b * T_LEN + t0) * D_INNER + c;
    float h[16] = {};
    float sumd = 0.f;
#pragma unroll 4
    for (int t = 0; t < CHUNK_L; ++t) {
        float dv = bf2f(dp[(size_t)t * D_INNER]);
        float uv = bf2f(up[(size_t)t * D_INNER]);
        float du = dv * uv;
        sumd += dv;
#pragma unroll
        for (int s = 0; s < 16; ++s) {
            float da = __expf(dv * A[s]);
            h[s] = fmaf(da, h[s], du * bc[t][s]);
        }
    }
    size_t o = ((size_t)((b * NCHUNK + chunk) * D_INNER) + c) * 16;
#pragma unroll
    for (int s4 = 0; s4 < 4; ++s4) {
        float4 hv = {h[s4 * 4], h[s4 * 4 + 1], h[s4 * 4 + 2], h[s4 * 4 + 3]};
        *(float4*)(Hbuf + o + s4 * 4) = hv;
        float4 pv = {__expf(A[s4 * 4] * sumd), __expf(A[s4 * 4 + 1] * sumd),
                     __expf(A[s4 * 4 + 2] * sumd), __expf(A[s4 * 4 + 3] * sumd)};
        *(float4*)(Pbuf + o + s4 * 4) = pv;
    }
}

__global__ __launch_bounds__(256) void k_scan2(const float* __restrict__ Pbuf,
                                               const float* __restrict__ Hbuf,
                                               float* __restrict__ Sbuf) {
    int idx = blockIdx.x * 256 + threadIdx.x;  // 0..65535 = (b, c*16+s)
    int b = idx >> 15, r = idx & 32767;
    size_t base = (size_t)b * NCHUNK * (D_INNER * 16) + r;
    float p[NCHUNK], hl[NCHUNK];
#pragma unroll
    for (int ch = 0; ch < NCHUNK; ++ch) {
        size_t o = base + (size_t)ch * (D_INNER * 16);
        p[ch] = Pbuf[o];
        hl[ch] = Hbuf[o];
    }
    float h = 0.f;
#pragma unroll
    for (int ch = 0; ch < NCHUNK; ++ch) {
        Sbuf[base + (size_t)ch * (D_INNER * 16)] = h;
        h = fmaf(p[ch], h, hl[ch]);
    }
}

__global__ __launch_bounds__(256) void k_scan3(const unsigned short* __restrict__ delta,
                                               const unsigned short* __restrict__ ub,
                                               const float* __restrict__ dbc,
                                               const unsigned short* __restrict__ xz,  // z-half pre-silu'd
                                               const float* __restrict__ A_log,
                                               const float* __restrict__ Dp,
                                               const float* __restrict__ Sbuf,
                                               unsigned short* __restrict__ yb) {
    int tid = threadIdx.x;
    int c = blockIdx.x * 256 + tid;
    int b = blockIdx.y >> 5, chunk = blockIdx.y & 31;
    int t0 = chunk * CHUNK_L;
    __shared__ float bc[CHUNK_L][32];
    {
        int t = tid >> 3, col = (tid & 7) * 4;
        const float* src = dbc + ((size_t)b * T_LEN + t0 + t) * XPROJ_LD + DT_RANK + col;
        *(float4*)&bc[t][col] = *(const float4*)src;
    }
    __syncthreads();
    float A[16];
#pragma unroll
    for (int s4 = 0; s4 < 4; ++s4) {
        float4 av = *(const float4*)(A_log + (size_t)c * D_STATE + s4 * 4);
        A[s4 * 4 + 0] = -__expf(av.x);
        A[s4 * 4 + 1] = -__expf(av.y);
        A[s4 * 4 + 2] = -__expf(av.z);
        A[s4 * 4 + 3] = -__expf(av.w);
    }
    float Dc = Dp[c];
    float h[16];
    size_t ho = ((size_t)((b * NCHUNK + chunk) * D_INNER) + c) * 16;
#pragma unroll
    for (int s4 = 0; s4 < 4; ++s4) {
        float4 hv = *(const float4*)(Sbuf + ho + s4 * 4);
        h[s4 * 4] = hv.x; h[s4 * 4 + 1] = hv.y; h[s4 * 4 + 2] = hv.z; h[s4 * 4 + 3] = hv.w;
    }
    const unsigned short* dp = delta + ((size_t)b * T_LEN + t0) * D_INNER + c;
    const unsigned short* up = ub + ((size_t)b * T_LEN + t0) * D_INNER + c;
    const unsigned short* zp = xz + ((size_t)b * T_LEN + t0) * 2 * D_INNER + D_INNER + c;
    unsigned short* yp = yb + ((size_t)b * T_LEN + t0) * D_INNER + c;
#pragma unroll 2
    for (int t = 0; t < CHUNK_L; ++t) {
        float dv = bf2f(dp[(size_t)t * D_INNER]);
        float uv = bf2f(up[(size_t)t * D_INNER]);
        float sz = bf2f(zp[(size_t)t * 2 * D_INNER]);  // already silu(z)
        float du = dv * uv;
        float y = Dc * uv;
#pragma unroll
        for (int s = 0; s < 16; ++s) {
            float da = __expf(dv * A[s]);
            h[s] = fmaf(da, h[s], du * bc[t][s]);
            y = fmaf(h[s], bc[t][16 + s], y);
        }
        yp[(size_t)t * D_INNER] = (unsigned short)f2bf_u(y * sz);
    }
}

extern "C" void kernel_launch(void* const* d_in, const int* in_sizes, int n_in,
                              void* d_out, int out_size, void* d_ws, size_t ws_size,
                              hipStream_t stream) {
    const float* x         = (const float*)d_in[0];
    const float* norm_w    = (const float*)d_in[1];
    const float* in_proj_w = (const float*)d_in[2];
    const float* conv_w    = (const float*)d_in[3];
    const float* conv_b    = (const float*)d_in[4];
    const float* x_proj_w  = (const float*)d_in[5];
    const float* dt_proj_w = (const float*)d_in[6];
    const float* dt_proj_b = (const float*)d_in[7];
    const float* A_log     = (const float*)d_in[8];
    const float* D_param   = (const float*)d_in[9];
    const float* out_proj_w= (const float*)d_in[10];
    float* out = (float*)d_out;

    // workspace layout (float units), flat; total 25,690,112 floats = 102.8 MB
    float* ws = (float*)d_ws;
    unsigned short* xzb    = (unsigned short*)(ws);            // 2048*4096 bf16 (z-half silu'd)
    unsigned short* ub     = (unsigned short*)(ws + 4194304);  // 2048*2048 bf16
    unsigned short* yb     = (unsigned short*)(ws + 6291456);  // 2048*2048 bf16
    unsigned short* partb  = (unsigned short*)(ws + 8388608);  // 32*2048*128 bf16
    float*          dbc    = ws + 12582912;                    // 2048*128 f32
    unsigned short* deltab = (unsigned short*)(ws + 12845056); // 2048*2048 bf16
    float*          Pbuf   = ws + 14942208;                    // 2*32*2048*16 f32
    float*          Hbuf   = ws + 17039360;                    // 2*32*2048*16 f32
    float*          Sbuf   = ws + 19136512;                    // 2*32*2048*16 f32
    unsigned short* wib    = (unsigned short*)(ws + 21233664); // 4096*1024 bf16
    unsigned short* wob    = (unsigned short*)(ws + 23330816); // 1024*2048 bf16
    unsigned short* wxb    = (unsigned short*)(ws + 24379392); // 128*2048 bf16
    unsigned short* wdtb   = (unsigned short*)(ws + 24510464); // 2048*64 bf16
    unsigned short* dtrawb = (unsigned short*)(ws + 24576000); // 2048*64 bf16
    unsigned short* xnb    = (unsigned short*)(ws + 24641536); // 2048*1024 bf16

    // 0. fused RMSNorm + all weight casts (one launch)
    k_prep<<<5312, 256, 0, stream>>>(x, norm_w, in_proj_w, out_proj_w, x_proj_w, dt_proj_w,
                                     xnb, (unsigned*)wib, (unsigned*)wob, (unsigned*)wxb,
                                     (unsigned*)wdtb);
    // 1. xz = xn @ in_proj_w^T (2048x4096x1024) -> bf16; z-half fused silu (512 blocks, 3/CU)
    gemm_bf16<128, 2, 3><<<dim3(NTOK / 128, 4096 / 128), 256, 0, stream>>>(
        xnb, wib, xzb, 2 * D_INNER, D_MODEL, nullptr);
    // 2. depthwise conv + SiLU -> ub
    k_conv<<<(NTOK * D_INNER) / 256, 256, 0, stream>>>(xzb, conv_w, conv_b, ub);
    // 3. x_dbc: split-K MFMA GEMM (32 slabs of K=64, 512 blocks) + reduce
    xproj_gemm<<<dim3(NTOK / 128, NSPLIT), 256, 0, stream>>>(ub, wxb, partb);
    k_xred<<<(NTOK * XPROJ_LD) / 1024, 256, 0, stream>>>(partb, dbc, dtrawb);
    // 4. delta = softplus(dt_raw @ dt_proj_w^T + b) -> bf16 (BN=64: 512 blocks)
    gemm_bf16<64, 1, 1><<<dim3(NTOK / 128, D_INNER / 64), 256, 0, stream>>>(
        dtrawb, wdtb, deltab, D_INNER, DT_RANK, dt_proj_b);
    // 5. chunked selective scan -> yb (bf16)
    k_scan1<<<dim3(D_INNER / 256, B_SZ * NCHUNK), 256, 0, stream>>>(deltab, ub, dbc, A_log,
                                                                    Pbuf, Hbuf);
    k_scan2<<<(B_SZ * D_INNER * D_STATE) / 256, 256, 0, stream>>>(Pbuf, Hbuf, Sbuf);
    k_scan3<<<dim3(D_INNER / 256, B_SZ * NCHUNK), 256, 0, stream>>>(deltab, ub, dbc, xzb, A_log,
                                                                    D_param, Sbuf, yb);
    // 6. out = y @ out_proj_w^T + x (2048x1024x2048), 64x64 tiles (512 blocks, 4/CU)
    gemm_sq64<<<dim3(NTOK / 64, D_MODEL / 64), 256, 0, stream>>>(
        yb, wob, out, D_MODEL, D_INNER, x);

    (void)in_sizes; (void)n_in; (void)out_size; (void)ws_size;
}

// Round 12
// 258.483 us; speedup vs baseline: 1.0042x; 1.0042x over previous
//
#include <hip/hip_runtime.h>
#include <math.h>

#define B_SZ 2
#define T_LEN 1024
#define D_MODEL 1024
#define D_STATE 16
#define D_INNER 2048
#define DT_RANK 64
#define NTOK (B_SZ * T_LEN)               // 2048 tokens
#define XPROJ_OUT 96
#define XPROJ_LD 128                      // padded leading dim for dbc
#define NCHUNK 32
#define CHUNK_L (T_LEN / NCHUNK)          // 32
#define NSPLIT 32                         // split-K for x_proj (K-slab 64)

typedef __attribute__((ext_vector_type(8))) short bf16x8;
typedef __attribute__((ext_vector_type(4))) float f32x4;

__device__ __forceinline__ float sigmoidf_(float x) { return 1.f / (1.f + __expf(-x)); }

__device__ __forceinline__ unsigned f2bf_u(float f) {  // RNE f32->bf16 bits
    unsigned u = __float_as_uint(f);
    return (u + 0x7FFFu + ((u >> 16) & 1u)) >> 16;
}
__device__ __forceinline__ float bf2f(unsigned short u) {
    return __uint_as_float((unsigned)u << 16);
}

__device__ __forceinline__ void gload_lds16(const void* g, void* l) {
    __builtin_amdgcn_global_load_lds((const __attribute__((address_space(1))) unsigned*)g,
                                     (__attribute__((address_space(3))) unsigned*)l,
                                     16, 0, 0);
}

// ---------------- fused prep: RMSNorm + all weight casts, one launch ----------------
__global__ __launch_bounds__(256) void k_prep(const float* __restrict__ x,
                                              const float* __restrict__ norm_w,
                                              const float* __restrict__ w_in,
                                              const float* __restrict__ w_out,
                                              const float* __restrict__ w_x,
                                              const float* __restrict__ w_dt,
                                              unsigned short* __restrict__ xn,
                                              unsigned* __restrict__ wib,
                                              unsigned* __restrict__ wob,
                                              unsigned* __restrict__ wxb,
                                              unsigned* __restrict__ wdtb) {
    __shared__ float red[4];
    int blk = blockIdx.x;
    if (blk < 2048) {  // RMSNorm row
        const float* xr = x + (size_t)blk * D_MODEL;
        int i = threadIdx.x * 4;
        float4 xv = *(const float4*)(xr + i);
        float s = xv.x * xv.x + xv.y * xv.y + xv.z * xv.z + xv.w * xv.w;
#pragma unroll
        for (int m = 1; m <= 32; m <<= 1) s += __shfl_xor(s, m);
        if ((threadIdx.x & 63) == 0) red[threadIdx.x >> 6] = s;
        __syncthreads();
        float tot = red[0] + red[1] + red[2] + red[3];
        float scale = rsqrtf(tot * (1.f / D_MODEL) + 1.1920929e-07f);
        float4 wv = *(const float4*)(norm_w + i);
        uint2 o;
        o.x = f2bf_u(xv.x * scale * wv.x) | (f2bf_u(xv.y * scale * wv.y) << 16);
        o.y = f2bf_u(xv.z * scale * wv.z) | (f2bf_u(xv.w * scale * wv.w) << 16);
        *(uint2*)(xn + (size_t)blk * D_MODEL + i) = o;
        return;
    }
    blk -= 2048;
    const float* src;
    unsigned* dst;
    int lidx;  // index in units of 8 elems
    if (blk < 2048) {
        src = w_in; dst = wib; lidx = blk * 256 + threadIdx.x;
    } else if (blk < 3072) {
        src = w_out; dst = wob; lidx = (blk - 2048) * 256 + threadIdx.x;
    } else if (blk < 3200) {
        dst = wxb; lidx = (blk - 3072) * 256 + threadIdx.x;
        if (lidx * 8 >= 96 * 2048) {  // pad rows 96..127 with zeros
            uint4 z = {0, 0, 0, 0};
            ((uint4*)dst)[lidx] = z;
            return;
        }
        src = w_x;
    } else {
        src = w_dt; dst = wdtb; lidx = (blk - 3200) * 256 + threadIdx.x;
    }
    float4 a = ((const float4*)src)[lidx * 2];
    float4 b = ((const float4*)src)[lidx * 2 + 1];
    uint4 o;
    o.x = f2bf_u(a.x) | (f2bf_u(a.y) << 16);
    o.y = f2bf_u(a.z) | (f2bf_u(a.w) << 16);
    o.z = f2bf_u(b.x) | (f2bf_u(b.y) << 16);
    o.w = f2bf_u(b.z) | (f2bf_u(b.w) << 16);
    ((uint4*)dst)[lidx] = o;
}

// ---------------- bf16 MFMA GEMM, BM=128, BK=64: C = A(MxK) * B(NxK)^T ----------------
// EPI: 1 = softplus(v + res[col]) bf16 out; 3 = bf16 out, silu when n0 >= D_INNER.
template <int BN, int CW, int EPI>
__global__ __launch_bounds__(256) void gemm_bf16(const unsigned short* __restrict__ A,
                                                 const unsigned short* __restrict__ B,
                                                 void* __restrict__ Cv, int ldc, int K,
                                                 const float* __restrict__ res) {
    constexpr int RW = 4 / CW;
    constexpr int MI = (128 / RW) / 16;
    constexpr int NJ = (BN / CW) / 16;
    __shared__ __align__(16) unsigned short As[128 * 64];
    __shared__ __align__(16) unsigned short Bs[BN * 64];
    int tid = threadIdx.x;
    int lane = tid & 63, wv = tid >> 6;
    int wr = wv / CW, wc = wv % CW;
    int lm = lane & 15, q = lane >> 4;
    int m0 = blockIdx.x * 128, n0 = blockIdx.y * BN;
    f32x4 acc[MI][NJ] = {};
    for (int k0 = 0; k0 < K; k0 += 64) {
#pragma unroll
        for (int it = 0; it < 4; ++it) {
            int chunk = it * 256 + tid;
            const unsigned short* g = A + (size_t)(m0 + (chunk >> 3)) * K + k0 + (chunk & 7) * 8;
            char* l = (char*)As + (it * 256 + wv * 64) * 16 + lane * 16;
            gload_lds16(g, l);
        }
#pragma unroll
        for (int it = 0; it < BN / 32; ++it) {
            int chunk = it * 256 + tid;
            const unsigned short* g = B + (size_t)(n0 + (chunk >> 3)) * K + k0 + (chunk & 7) * 8;
            char* l = (char*)Bs + (it * 256 + wv * 64) * 16 + lane * 16;
            gload_lds16(g, l);
        }
        __syncthreads();
#pragma unroll
        for (int h = 0; h < 2; ++h) {
            bf16x8 af[MI], bfr[NJ];
#pragma unroll
            for (int i = 0; i < MI; ++i)
                af[i] = *(const bf16x8*)(As + (wr * MI * 16 + i * 16 + lm) * 64 + h * 32 + q * 8);
#pragma unroll
            for (int j = 0; j < NJ; ++j)
                bfr[j] = *(const bf16x8*)(Bs + (wc * NJ * 16 + j * 16 + lm) * 64 + h * 32 + q * 8);
#pragma unroll
            for (int i = 0; i < MI; ++i)
#pragma unroll
                for (int j = 0; j < NJ; ++j)
                    acc[i][j] = __builtin_amdgcn_mfma_f32_16x16x32_bf16(af[i], bfr[j], acc[i][j], 0, 0, 0);
        }
        __syncthreads();
    }
#pragma unroll
    for (int i = 0; i < MI; ++i) {
#pragma unroll
        for (int j = 0; j < NJ; ++j) {
#pragma unroll
            for (int r = 0; r < 4; ++r) {
                int row = m0 + wr * MI * 16 + i * 16 + q * 4 + r;
                int col = n0 + wc * NJ * 16 + j * 16 + lm;
                float v = acc[i][j][r];
                if (EPI == 1) {
                    v += res[col];
                    v = (v > 20.f) ? v : log1pf(__expf(v));
                    ((unsigned short*)Cv)[(size_t)row * ldc + col] = (unsigned short)f2bf_u(v);
                } else {  // EPI == 3
                    if (n0 >= D_INNER) v = v * sigmoidf_(v);  // fused silu(z)
                    ((unsigned short*)Cv)[(size_t)row * ldc + col] = (unsigned short)f2bf_u(v);
                }
            }
        }
    }
}

// ---------------- 64x64-tile bf16 MFMA GEMM (out_proj): C = A*B^T + res, f32 out ----------------
__global__ __launch_bounds__(256) void gemm_sq64(const unsigned short* __restrict__ A,
                                                 const unsigned short* __restrict__ B,
                                                 float* __restrict__ C, int ldc, int K,
                                                 const float* __restrict__ res) {
    __shared__ __align__(16) unsigned short As[64 * 64];
    __shared__ __align__(16) unsigned short Bs[64 * 64];
    int tid = threadIdx.x;
    int lane = tid & 63, wv = tid >> 6;
    int wr = wv >> 1, wc = wv & 1;
    int lm = lane & 15, q = lane >> 4;
    int m0 = blockIdx.x * 64, n0 = blockIdx.y * 64;
    f32x4 acc[2][2] = {};
    for (int k0 = 0; k0 < K; k0 += 64) {
#pragma unroll
        for (int it = 0; it < 2; ++it) {
            int chunk = it * 256 + tid;
            const unsigned short* g = A + (size_t)(m0 + (chunk >> 3)) * K + k0 + (chunk & 7) * 8;
            char* l = (char*)As + (it * 256 + wv * 64) * 16 + lane * 16;
            gload_lds16(g, l);
        }
#pragma unroll
        for (int it = 0; it < 2; ++it) {
            int chunk = it * 256 + tid;
            const unsigned short* g = B + (size_t)(n0 + (chunk >> 3)) * K + k0 + (chunk & 7) * 8;
            char* l = (char*)Bs + (it * 256 + wv * 64) * 16 + lane * 16;
            gload_lds16(g, l);
        }
        __syncthreads();
#pragma unroll
        for (int h = 0; h < 2; ++h) {
            bf16x8 af[2], bfr[2];
#pragma unroll
            for (int i = 0; i < 2; ++i)
                af[i] = *(const bf16x8*)(As + (wr * 32 + i * 16 + lm) * 64 + h * 32 + q * 8);
#pragma unroll
            for (int j = 0; j < 2; ++j)
                bfr[j] = *(const bf16x8*)(Bs + (wc * 32 + j * 16 + lm) * 64 + h * 32 + q * 8);
#pragma unroll
            for (int i = 0; i < 2; ++i)
#pragma unroll
                for (int j = 0; j < 2; ++j)
                    acc[i][j] = __builtin_amdgcn_mfma_f32_16x16x32_bf16(af[i], bfr[j], acc[i][j], 0, 0, 0);
        }
        __syncthreads();
    }
#pragma unroll
    for (int i = 0; i < 2; ++i)
#pragma unroll
        for (int j = 0; j < 2; ++j)
#pragma unroll
            for (int r = 0; r < 4; ++r) {
                int row = m0 + wr * 32 + i * 16 + q * 4 + r;
                int col = n0 + wc * 32 + j * 16 + lm;
                C[(size_t)row * ldc + col] = acc[i][j][r] + res[(size_t)row * ldc + col];
            }
}

// ---------------- x_proj split-K MFMA GEMM (K-slab 64, single stage) -> bf16 partials ----------------
__global__ __launch_bounds__(256) void xproj_gemm(const unsigned short* __restrict__ A,
                                                  const unsigned short* __restrict__ B,
                                                  unsigned short* __restrict__ part) {
    constexpr int MI = 4, NJ = 4;
    __shared__ __align__(16) unsigned short As[128 * 64];
    __shared__ __align__(16) unsigned short Bs[128 * 64];
    int tid = threadIdx.x;
    int lane = tid & 63, wv = tid >> 6;
    int wr = wv >> 1, wc = wv & 1;
    int lm = lane & 15, q = lane >> 4;
    int m0 = blockIdx.x * 128;
    int k0 = blockIdx.y * 64;
    f32x4 acc[MI][NJ] = {};
#pragma unroll
    for (int it = 0; it < 4; ++it) {
        int chunk = it * 256 + tid;
        const unsigned short* g = A + (size_t)(m0 + (chunk >> 3)) * D_INNER + k0 + (chunk & 7) * 8;
        char* l = (char*)As + (it * 256 + wv * 64) * 16 + lane * 16;
        gload_lds16(g, l);
    }
#pragma unroll
    for (int it = 0; it < 4; ++it) {
        int chunk = it * 256 + tid;
        const unsigned short* g = B + (size_t)(chunk >> 3) * D_INNER + k0 + (chunk & 7) * 8;
        char* l = (char*)Bs + (it * 256 + wv * 64) * 16 + lane * 16;
        gload_lds16(g, l);
    }
    __syncthreads();
#pragma unroll
    for (int h = 0; h < 2; ++h) {
        bf16x8 af[MI], bfr[NJ];
#pragma unroll
        for (int i = 0; i < MI; ++i)
            af[i] = *(const bf16x8*)(As + (wr * 64 + i * 16 + lm) * 64 + h * 32 + q * 8);
#pragma unroll
        for (int j = 0; j < NJ; ++j)
            bfr[j] = *(const bf16x8*)(Bs + (wc * 64 + j * 16 + lm) * 64 + h * 32 + q * 8);
#pragma unroll
        for (int i = 0; i < MI; ++i)
#pragma unroll
            for (int j = 0; j < NJ; ++j)
                acc[i][j] = __builtin_amdgcn_mfma_f32_16x16x32_bf16(af[i], bfr[j], acc[i][j], 0, 0, 0);
    }
    unsigned short* dst = part + (size_t)blockIdx.y * (NTOK * XPROJ_LD);
#pragma unroll
    for (int i = 0; i < MI; ++i)
#pragma unroll
        for (int j = 0; j < NJ; ++j)
#pragma unroll
            for (int r = 0; r < 4; ++r) {
                int row = m0 + wr * 64 + i * 16 + q * 4 + r;
                int col = wc * 64 + j * 16 + lm;
                dst[(size_t)row * XPROJ_LD + col] = (unsigned short)f2bf_u(acc[i][j][r]);
            }
}

// ---------------- reduce split-K partials (4 elems/thread); emit dbc f32 + dt_raw bf16 ----------------
__global__ __launch_bounds__(256) void k_xred(const unsigned short* __restrict__ part,
                                              float* __restrict__ dbc,
                                              unsigned short* __restrict__ dtrawb) {
    int idx4 = blockIdx.x * 256 + threadIdx.x;  // unit of 4 elems
    float s0 = 0.f, s1 = 0.f, s2 = 0.f, s3 = 0.f;
#pragma unroll
    for (int sp = 0; sp < NSPLIT; ++sp) {
        uint2 v = *(const uint2*)(part + (size_t)sp * (NTOK * XPROJ_LD) + idx4 * 4);
        s0 += __uint_as_float(v.x << 16);
        s1 += __uint_as_float(v.x & 0xFFFF0000u);
        s2 += __uint_as_float(v.y << 16);
        s3 += __uint_as_float(v.y & 0xFFFF0000u);
    }
    float4 sv = {s0, s1, s2, s3};
    *(float4*)(dbc + idx4 * 4) = sv;
    int col = (idx4 * 4) & (XPROJ_LD - 1);
    if (col < DT_RANK) {
        int row = (idx4 * 4) >> 7;
        uint2 o;
        o.x = f2bf_u(s0) | (f2bf_u(s1) << 16);
        o.y = f2bf_u(s2) | (f2bf_u(s3) << 16);
        *(uint2*)(dtrawb + (size_t)row * DT_RANK + col) = o;
    }
}

// ---------------- depthwise causal conv (k=4, bf16 in) + SiLU -> ub ----------------
__global__ __launch_bounds__(256) void k_conv(const unsigned short* __restrict__ xz,
                                              const float* __restrict__ cw,
                                              const float* __restrict__ cb,
                                              unsigned short* __restrict__ ub) {
    int idx = blockIdx.x * 256 + threadIdx.x;
    int c = idx & (D_INNER - 1);
    int t = (idx >> 11) & (T_LEN - 1);
    int b = idx >> 21;
    const unsigned short* xs = xz + (size_t)b * T_LEN * 2 * D_INNER + c;
    float4 wv = *(const float4*)(cw + c * 4);
    float s = cb[c];
    if (t >= 3) s = fmaf(bf2f(xs[(size_t)(t - 3) * 2 * D_INNER]), wv.x, s);
    if (t >= 2) s = fmaf(bf2f(xs[(size_t)(t - 2) * 2 * D_INNER]), wv.y, s);
    if (t >= 1) s = fmaf(bf2f(xs[(size_t)(t - 1) * 2 * D_INNER]), wv.z, s);
    s = fmaf(bf2f(xs[(size_t)t * 2 * D_INNER]), wv.w, s);
    float v = s * sigmoidf_(s);
    ub[idx] = (unsigned short)f2bf_u(v);
}

// ---------------- chunked selective scan, lane-per-channel (3 kernels, proven) ----------------
__global__ __launch_bounds__(256) void k_scan1(const unsigned short* __restrict__ delta,
                                               const unsigned short* __restrict__ ub,
                                               const float* __restrict__ dbc,
                                               const float* __restrict__ A_log,
                                               float* __restrict__ Pbuf,
                                               float* __restrict__ Hbuf) {
    int tid = threadIdx.x;
    int c = blockIdx.x * 256 + tid;
    int b = blockIdx.y >> 5, chunk = blockIdx.y & 31;
    int t0 = chunk * CHUNK_L;
    __shared__ float bc[CHUNK_L][32];  // [t][0:16]=B, [t][16:32]=C
    {
        int t = tid >> 3, col = (tid & 7) * 4;
        const float* src = dbc + ((size_t)b * T_LEN + t0 + t) * XPROJ_LD + DT_RANK + col;
        *(float4*)&bc[t][col] = *(const float4*)src;
    }
    __syncthreads();
    float A[16];
#pragma unroll
    for (int s4 = 0; s4 < 4; ++s4) {
        float4 av = *(const float4*)(A_log + (size_t)c * D_STATE + s4 * 4);
        A[s4 * 4 + 0] = -__expf(av.x);
        A[s4 * 4 + 1] = -__expf(av.y);
        A[s4 * 4 + 2] = -__expf(av.z);
        A[s4 * 4 + 3] = -__expf(av.w);
    }
    const unsigned short* dp = delta + ((size_t)b * T_LEN + t0) * D_INNER + c;
    const unsigned short* up = ub + ((size_t)b * T_LEN + t0) * D_INNER + c;
    float h[16] = {};
    float sumd = 0.f;
#pragma unroll 4
    for (int t = 0; t < CHUNK_L; ++t) {
        float dv = bf2f(dp[(size_t)t * D_INNER]);
        float uv = bf2f(up[(size_t)t * D_INNER]);
        float du = dv * uv;
        sumd += dv;
#pragma unroll
        for (int s = 0; s < 16; ++s) {
            float da = __expf(dv * A[s]);
            h[s] = fmaf(da, h[s], du * bc[t][s]);
        }
    }
    size_t o = ((size_t)((b * NCHUNK + chunk) * D_INNER) + c) * 16;
#pragma unroll
    for (int s4 = 0; s4 < 4; ++s4) {
        float4 hv = {h[s4 * 4], h[s4 * 4 + 1], h[s4 * 4 + 2], h[s4 * 4 + 3]};
        *(float4*)(Hbuf + o + s4 * 4) = hv;
        float4 pv = {__expf(A[s4 * 4] * sumd), __expf(A[s4 * 4 + 1] * sumd),
                     __expf(A[s4 * 4 + 2] * sumd), __expf(A[s4 * 4 + 3] * sumd)};
        *(float4*)(Pbuf + o + s4 * 4) = pv;
    }
}

__global__ __launch_bounds__(256) void k_scan2(const float* __restrict__ Pbuf,
                                               const float* __restrict__ Hbuf,
                                               float* __restrict__ Sbuf) {
    int idx = blockIdx.x * 256 + threadIdx.x;  // 0..65535 = (b, c*16+s)
    int b = idx >> 15, r = idx & 32767;
    size_t base = (size_t)b * NCHUNK * (D_INNER * 16) + r;
    float p[NCHUNK], hl[NCHUNK];
#pragma unroll
    for (int ch = 0; ch < NCHUNK; ++ch) {
        size_t o = base + (size_t)ch * (D_INNER * 16);
        p[ch] = Pbuf[o];
        hl[ch] = Hbuf[o];
    }
    float h = 0.f;
#pragma unroll
    for (int ch = 0; ch < NCHUNK; ++ch) {
        Sbuf[base + (size_t)ch * (D_INNER * 16)] = h;
        h = fmaf(p[ch], h, hl[ch]);
    }
}

__global__ __launch_bounds__(256) void k_scan3(const unsigned short* __restrict__ delta,
                                               const unsigned short* __restrict__ ub,
                                               const float* __restrict__ dbc,
                                               const unsigned short* __restrict__ xz,  // z-half pre-silu'd
                                               const float* __restrict__ A_log,
                                               const float* __restrict__ Dp,
                                               const float* __restrict__ Sbuf,
                                               unsigned short* __restrict__ yb) {
    int tid = threadIdx.x;
    int c = blockIdx.x * 256 + tid;
    int b = blockIdx.y >> 5, chunk = blockIdx.y & 31;
    int t0 = chunk * CHUNK_L;
    __shared__ float bc[CHUNK_L][32];
    {
        int t = tid >> 3, col = (tid & 7) * 4;
        const float* src = dbc + ((size_t)b * T_LEN + t0 + t) * XPROJ_LD + DT_RANK + col;
        *(float4*)&bc[t][col] = *(const float4*)src;
    }
    __syncthreads();
    float A[16];
#pragma unroll
    for (int s4 = 0; s4 < 4; ++s4) {
        float4 av = *(const float4*)(A_log + (size_t)c * D_STATE + s4 * 4);
        A[s4 * 4 + 0] = -__expf(av.x);
        A[s4 * 4 + 1] = -__expf(av.y);
        A[s4 * 4 + 2] = -__expf(av.z);
        A[s4 * 4 + 3] = -__expf(av.w);
    }
    float Dc = Dp[c];
    float h[16];
    size_t ho = ((size_t)((b * NCHUNK + chunk) * D_INNER) + c) * 16;
#pragma unroll
    for (int s4 = 0; s4 < 4; ++s4) {
        float4 hv = *(const float4*)(Sbuf + ho + s4 * 4);
        h[s4 * 4] = hv.x; h[s4 * 4 + 1] = hv.y; h[s4 * 4 + 2] = hv.z; h[s4 * 4 + 3] = hv.w;
    }
    const unsigned short* dp = delta + ((size_t)b * T_LEN + t0) * D_INNER + c;
    const unsigned short* up = ub + ((size_t)b * T_LEN + t0) * D_INNER + c;
    const unsigned short* zp = xz + ((size_t)b * T_LEN + t0) * 2 * D_INNER + D_INNER + c;
    unsigned short* yp = yb + ((size_t)b * T_LEN + t0) * D_INNER + c;
#pragma unroll 2
    for (int t = 0; t < CHUNK_L; ++t) {
        float dv = bf2f(dp[(size_t)t * D_INNER]);
        float uv = bf2f(up[(size_t)t * D_INNER]);
        float sz = bf2f(zp[(size_t)t * 2 * D_INNER]);  // already silu(z)
        float du = dv * uv;
        float y = Dc * uv;
#pragma unroll
        for (int s = 0; s < 16; ++s) {
            float da = __expf(dv * A[s]);
            h[s] = fmaf(da, h[s], du * bc[t][s]);
            y = fmaf(h[s], bc[t][16 + s], y);
        }
        yp[(size_t)t * D_INNER] = (unsigned short)f2bf_u(y * sz);
    }
}

extern "C" void kernel_launch(void* const* d_in, const int* in_sizes, int n_in,
                              void* d_out, int out_size, void* d_ws, size_t ws_size,
                              hipStream_t stream) {
    const float* x         = (const float*)d_in[0];
    const float* norm_w    = (const float*)d_in[1];
    const float* in_proj_w = (const float*)d_in[2];
    const float* conv_w    = (const float*)d_in[3];
    const float* conv_b    = (const float*)d_in[4];
    const float* x_proj_w  = (const float*)d_in[5];
    const float* dt_proj_w = (const float*)d_in[6];
    const float* dt_proj_b = (const float*)d_in[7];
    const float* A_log     = (const float*)d_in[8];
    const float* D_param   = (const float*)d_in[9];
    const float* out_proj_w= (const float*)d_in[10];
    float* out = (float*)d_out;

    // workspace layout (float units), flat; total 25,690,112 floats = 102.8 MB
    float* ws = (float*)d_ws;
    unsigned short* xzb    = (unsigned short*)(ws);            // 2048*4096 bf16 (z-half silu'd)
    unsigned short* ub     = (unsigned short*)(ws + 4194304);  // 2048*2048 bf16
    unsigned short* yb     = (unsigned short*)(ws + 6291456);  // 2048*2048 bf16
    unsigned short* partb  = (unsigned short*)(ws + 8388608);  // 32*2048*128 bf16
    float*          dbc    = ws + 12582912;                    // 2048*128 f32
    unsigned short* deltab = (unsigned short*)(ws + 12845056); // 2048*2048 bf16
    float*          Pbuf   = ws + 14942208;                    // 2*32*2048*16 f32
    float*          Hbuf   = ws + 17039360;                    // 2*32*2048*16 f32
    float*          Sbuf   = ws + 19136512;                    // 2*32*2048*16 f32
    unsigned short* wib    = (unsigned short*)(ws + 21233664); // 4096*1024 bf16
    unsigned short* wob    = (unsigned short*)(ws + 23330816); // 1024*2048 bf16
    unsigned short* wxb    = (unsigned short*)(ws + 24379392); // 128*2048 bf16
    unsigned short* wdtb   = (unsigned short*)(ws + 24510464); // 2048*64 bf16
    unsigned short* dtrawb = (unsigned short*)(ws + 24576000); // 2048*64 bf16
    unsigned short* xnb    = (unsigned short*)(ws + 24641536); // 2048*1024 bf16

    // 0. fused RMSNorm + all weight casts (one launch)
    k_prep<<<5312, 256, 0, stream>>>(x, norm_w, in_proj_w, out_proj_w, x_proj_w, dt_proj_w,
                                     xnb, (unsigned*)wib, (unsigned*)wob, (unsigned*)wxb,
                                     (unsigned*)wdtb);
    // 1. xz = xn @ in_proj_w^T (2048x4096x1024) -> bf16; z-half fused silu (512 blocks)
    gemm_bf16<128, 2, 3><<<dim3(NTOK / 128, 4096 / 128), 256, 0, stream>>>(
        xnb, wib, xzb, 2 * D_INNER, D_MODEL, nullptr);
    // 2. depthwise conv + SiLU -> ub
    k_conv<<<(NTOK * D_INNER) / 256, 256, 0, stream>>>(xzb, conv_w, conv_b, ub);
    // 3. x_dbc: split-K MFMA GEMM (32 slabs of K=64, 512 blocks) + reduce
    xproj_gemm<<<dim3(NTOK / 128, NSPLIT), 256, 0, stream>>>(ub, wxb, partb);
    k_xred<<<(NTOK * XPROJ_LD) / 1024, 256, 0, stream>>>(partb, dbc, dtrawb);
    // 4. delta = softplus(dt_raw @ dt_proj_w^T + b) -> bf16 (BN=64: 512 blocks)
    gemm_bf16<64, 1, 1><<<dim3(NTOK / 128, D_INNER / 64), 256, 0, stream>>>(
        dtrawb, wdtb, deltab, D_INNER, DT_RANK, dt_proj_b);
    // 5. chunked selective scan (3 kernels — proven correct ordering) -> yb
    k_scan1<<<dim3(D_INNER / 256, B_SZ * NCHUNK), 256, 0, stream>>>(deltab, ub, dbc, A_log,
                                                                    Pbuf, Hbuf);
    k_scan2<<<(B_SZ * D_INNER * D_STATE) / 256, 256, 0, stream>>>(Pbuf, Hbuf, Sbuf);
    k_scan3<<<dim3(D_INNER / 256, B_SZ * NCHUNK), 256, 0, stream>>>(deltab, ub, dbc, xzb, A_log,
                                                                    D_param, Sbuf, yb);
    // 6. out = y @ out_proj_w^T + x (2048x1024x2048), 64x64 tiles (512 blocks)
    gemm_sq64<<<dim3(NTOK / 64, D_MODEL / 64), 256, 0, stream>>>(
        yb, wob, out, D_MODEL, D_INNER, x);

    (void)in_sizes; (void)n_in; (void)out_size; (void)ws_size;
}

// Round 13
// 249.199 us; speedup vs baseline: 1.0416x; 1.0373x over previous
//
#include <hip/hip_runtime.h>
#include <math.h>

#define B_SZ 2
#define T_LEN 1024
#define D_MODEL 1024
#define D_STATE 16
#define D_INNER 2048
#define DT_RANK 64
#define NTOK (B_SZ * T_LEN)               // 2048 tokens
#define XPROJ_OUT 96
#define XPROJ_LD 128                      // padded leading dim for dbc
#define NCHUNK 32
#define CHUNK_L (T_LEN / NCHUNK)          // 32
#define NSPLIT 32                         // split-K for x_proj (K-slab 64)

typedef __attribute__((ext_vector_type(8))) short bf16x8;
typedef __attribute__((ext_vector_type(4))) float f32x4;

__device__ __forceinline__ float sigmoidf_(float x) { return 1.f / (1.f + __expf(-x)); }

__device__ __forceinline__ unsigned f2bf_u(float f) {  // RNE f32->bf16 bits
    unsigned u = __float_as_uint(f);
    return (u + 0x7FFFu + ((u >> 16) & 1u)) >> 16;
}
__device__ __forceinline__ float bf2f(unsigned short u) {
    return __uint_as_float((unsigned)u << 16);
}

__device__ __forceinline__ void gload_lds16(const void* g, void* l) {
    __builtin_amdgcn_global_load_lds((const __attribute__((address_space(1))) unsigned*)g,
                                     (__attribute__((address_space(3))) unsigned*)l,
                                     16, 0, 0);
}

// ---------------- fused prep: RMSNorm + all weight casts, one launch ----------------
__global__ __launch_bounds__(256) void k_prep(const float* __restrict__ x,
                                              const float* __restrict__ norm_w,
                                              const float* __restrict__ w_in,
                                              const float* __restrict__ w_out,
                                              const float* __restrict__ w_x,
                                              const float* __restrict__ w_dt,
                                              unsigned short* __restrict__ xn,
                                              unsigned* __restrict__ wib,
                                              unsigned* __restrict__ wob,
                                              unsigned* __restrict__ wxb,
                                              unsigned* __restrict__ wdtb) {
    __shared__ float red[4];
    int blk = blockIdx.x;
    if (blk < 2048) {  // RMSNorm row
        const float* xr = x + (size_t)blk * D_MODEL;
        int i = threadIdx.x * 4;
        float4 xv = *(const float4*)(xr + i);
        float s = xv.x * xv.x + xv.y * xv.y + xv.z * xv.z + xv.w * xv.w;
#pragma unroll
        for (int m = 1; m <= 32; m <<= 1) s += __shfl_xor(s, m);
        if ((threadIdx.x & 63) == 0) red[threadIdx.x >> 6] = s;
        __syncthreads();
        float tot = red[0] + red[1] + red[2] + red[3];
        float scale = rsqrtf(tot * (1.f / D_MODEL) + 1.1920929e-07f);
        float4 wv = *(const float4*)(norm_w + i);
        uint2 o;
        o.x = f2bf_u(xv.x * scale * wv.x) | (f2bf_u(xv.y * scale * wv.y) << 16);
        o.y = f2bf_u(xv.z * scale * wv.z) | (f2bf_u(xv.w * scale * wv.w) << 16);
        *(uint2*)(xn + (size_t)blk * D_MODEL + i) = o;
        return;
    }
    blk -= 2048;
    const float* src;
    unsigned* dst;
    int lidx;  // index in units of 8 elems
    if (blk < 2048) {
        src = w_in; dst = wib; lidx = blk * 256 + threadIdx.x;
    } else if (blk < 3072) {
        src = w_out; dst = wob; lidx = (blk - 2048) * 256 + threadIdx.x;
    } else if (blk < 3200) {
        dst = wxb; lidx = (blk - 3072) * 256 + threadIdx.x;
        if (lidx * 8 >= 96 * 2048) {  // pad rows 96..127 with zeros
            uint4 z = {0, 0, 0, 0};
            ((uint4*)dst)[lidx] = z;
            return;
        }
        src = w_x;
    } else {
        src = w_dt; dst = wdtb; lidx = (blk - 3200) * 256 + threadIdx.x;
    }
    float4 a = ((const float4*)src)[lidx * 2];
    float4 b = ((const float4*)src)[lidx * 2 + 1];
    uint4 o;
    o.x = f2bf_u(a.x) | (f2bf_u(a.y) << 16);
    o.y = f2bf_u(a.z) | (f2bf_u(a.w) << 16);
    o.z = f2bf_u(b.x) | (f2bf_u(b.y) << 16);
    o.w = f2bf_u(b.z) | (f2bf_u(b.w) << 16);
    ((uint4*)dst)[lidx] = o;
}

// XOR-swizzled LDS tile layout (rows of 64 bf16 = 8 chunks of 16B):
//   slot(r, c) = r*8 + (c ^ (r & 7))   — spreads fragment reads over all 32 banks.
// Staging: LDS slot p (= lane-contiguous) receives global chunk (p>>3, (p&7)^((p>>3)&7)).
// Reads: chunk index ci -> LDS offset r*64 + (ci ^ (r&7))*8 elems; r&7 == lm&7 here.

// ---------------- bf16 MFMA GEMM, BM=128, BK=64: C = A(MxK) * B(NxK)^T ----------------
// EPI: 1 = softplus(v + res[col]) bf16 out; 3 = bf16 out, silu when n0 >= D_INNER.
template <int BN, int CW, int EPI>
__global__ __launch_bounds__(256) void gemm_bf16(const unsigned short* __restrict__ A,
                                                 const unsigned short* __restrict__ B,
                                                 void* __restrict__ Cv, int ldc, int K,
                                                 const float* __restrict__ res) {
    constexpr int RW = 4 / CW;
    constexpr int MI = (128 / RW) / 16;
    constexpr int NJ = (BN / CW) / 16;
    __shared__ __align__(16) unsigned short As[128 * 64];
    __shared__ __align__(16) unsigned short Bs[BN * 64];
    int tid = threadIdx.x;
    int lane = tid & 63, wv = tid >> 6;
    int wr = wv / CW, wc = wv % CW;
    int lm = lane & 15, q = lane >> 4;
    int sw = lm & 7;
    int m0 = blockIdx.x * 128, n0 = blockIdx.y * BN;
    f32x4 acc[MI][NJ] = {};
    for (int k0 = 0; k0 < K; k0 += 64) {
#pragma unroll
        for (int it = 0; it < 4; ++it) {
            int chunk = it * 256 + tid;
            int cc = (chunk & 7) ^ ((chunk >> 3) & 7);  // swizzled source column-chunk
            const unsigned short* g = A + (size_t)(m0 + (chunk >> 3)) * K + k0 + cc * 8;
            char* l = (char*)As + (it * 256 + wv * 64) * 16 + lane * 16;
            gload_lds16(g, l);
        }
#pragma unroll
        for (int it = 0; it < BN / 32; ++it) {
            int chunk = it * 256 + tid;
            int cc = (chunk & 7) ^ ((chunk >> 3) & 7);
            const unsigned short* g = B + (size_t)(n0 + (chunk >> 3)) * K + k0 + cc * 8;
            char* l = (char*)Bs + (it * 256 + wv * 64) * 16 + lane * 16;
            gload_lds16(g, l);
        }
        __syncthreads();
#pragma unroll
        for (int h = 0; h < 2; ++h) {
            bf16x8 af[MI], bfr[NJ];
#pragma unroll
            for (int i = 0; i < MI; ++i)
                af[i] = *(const bf16x8*)(As + (wr * MI * 16 + i * 16 + lm) * 64 +
                                         (((h << 2) + q) ^ sw) * 8);
#pragma unroll
            for (int j = 0; j < NJ; ++j)
                bfr[j] = *(const bf16x8*)(Bs + (wc * NJ * 16 + j * 16 + lm) * 64 +
                                          (((h << 2) + q) ^ sw) * 8);
#pragma unroll
            for (int i = 0; i < MI; ++i)
#pragma unroll
                for (int j = 0; j < NJ; ++j)
                    acc[i][j] = __builtin_amdgcn_mfma_f32_16x16x32_bf16(af[i], bfr[j], acc[i][j], 0, 0, 0);
        }
        __syncthreads();
    }
#pragma unroll
    for (int i = 0; i < MI; ++i) {
#pragma unroll
        for (int j = 0; j < NJ; ++j) {
#pragma unroll
            for (int r = 0; r < 4; ++r) {
                int row = m0 + wr * MI * 16 + i * 16 + q * 4 + r;
                int col = n0 + wc * NJ * 16 + j * 16 + lm;
                float v = acc[i][j][r];
                if (EPI == 1) {
                    v += res[col];
                    v = (v > 20.f) ? v : log1pf(__expf(v));
                    ((unsigned short*)Cv)[(size_t)row * ldc + col] = (unsigned short)f2bf_u(v);
                } else {  // EPI == 3
                    if (n0 >= D_INNER) v = v * sigmoidf_(v);  // fused silu(z)
                    ((unsigned short*)Cv)[(size_t)row * ldc + col] = (unsigned short)f2bf_u(v);
                }
            }
        }
    }
}

// ---------------- 64x64-tile bf16 MFMA GEMM (out_proj): C = A*B^T + res, f32 out ----------------
__global__ __launch_bounds__(256) void gemm_sq64(const unsigned short* __restrict__ A,
                                                 const unsigned short* __restrict__ B,
                                                 float* __restrict__ C, int ldc, int K,
                                                 const float* __restrict__ res) {
    __shared__ __align__(16) unsigned short As[64 * 64];
    __shared__ __align__(16) unsigned short Bs[64 * 64];
    int tid = threadIdx.x;
    int lane = tid & 63, wv = tid >> 6;
    int wr = wv >> 1, wc = wv & 1;
    int lm = lane & 15, q = lane >> 4;
    int sw = lm & 7;
    int m0 = blockIdx.x * 64, n0 = blockIdx.y * 64;
    f32x4 acc[2][2] = {};
    for (int k0 = 0; k0 < K; k0 += 64) {
#pragma unroll
        for (int it = 0; it < 2; ++it) {
            int chunk = it * 256 + tid;
            int cc = (chunk & 7) ^ ((chunk >> 3) & 7);
            const unsigned short* g = A + (size_t)(m0 + (chunk >> 3)) * K + k0 + cc * 8;
            char* l = (char*)As + (it * 256 + wv * 64) * 16 + lane * 16;
            gload_lds16(g, l);
        }
#pragma unroll
        for (int it = 0; it < 2; ++it) {
            int chunk = it * 256 + tid;
            int cc = (chunk & 7) ^ ((chunk >> 3) & 7);
            const unsigned short* g = B + (size_t)(n0 + (chunk >> 3)) * K + k0 + cc * 8;
            char* l = (char*)Bs + (it * 256 + wv * 64) * 16 + lane * 16;
            gload_lds16(g, l);
        }
        __syncthreads();
#pragma unroll
        for (int h = 0; h < 2; ++h) {
            bf16x8 af[2], bfr[2];
#pragma unroll
            for (int i = 0; i < 2; ++i)
                af[i] = *(const bf16x8*)(As + (wr * 32 + i * 16 + lm) * 64 +
                                         (((h << 2) + q) ^ sw) * 8);
#pragma unroll
            for (int j = 0; j < 2; ++j)
                bfr[j] = *(const bf16x8*)(Bs + (wc * 32 + j * 16 + lm) * 64 +
                                          (((h << 2) + q) ^ sw) * 8);
#pragma unroll
            for (int i = 0; i < 2; ++i)
#pragma unroll
                for (int j = 0; j < 2; ++j)
                    acc[i][j] = __builtin_amdgcn_mfma_f32_16x16x32_bf16(af[i], bfr[j], acc[i][j], 0, 0, 0);
        }
        __syncthreads();
    }
#pragma unroll
    for (int i = 0; i < 2; ++i)
#pragma unroll
        for (int j = 0; j < 2; ++j)
#pragma unroll
            for (int r = 0; r < 4; ++r) {
                int row = m0 + wr * 32 + i * 16 + q * 4 + r;
                int col = n0 + wc * 32 + j * 16 + lm;
                C[(size_t)row * ldc + col] = acc[i][j][r] + res[(size_t)row * ldc + col];
            }
}

// ---------------- x_proj split-K MFMA GEMM (K-slab 64, single stage) -> bf16 partials ----------------
__global__ __launch_bounds__(256) void xproj_gemm(const unsigned short* __restrict__ A,
                                                  const unsigned short* __restrict__ B,
                                                  unsigned short* __restrict__ part) {
    constexpr int MI = 4, NJ = 4;
    __shared__ __align__(16) unsigned short As[128 * 64];
    __shared__ __align__(16) unsigned short Bs[128 * 64];
    int tid = threadIdx.x;
    int lane = tid & 63, wv = tid >> 6;
    int wr = wv >> 1, wc = wv & 1;
    int lm = lane & 15, q = lane >> 4;
    int sw = lm & 7;
    int m0 = blockIdx.x * 128;
    int k0 = blockIdx.y * 64;
    f32x4 acc[MI][NJ] = {};
#pragma unroll
    for (int it = 0; it < 4; ++it) {
        int chunk = it * 256 + tid;
        int cc = (chunk & 7) ^ ((chunk >> 3) & 7);
        const unsigned short* g = A + (size_t)(m0 + (chunk >> 3)) * D_INNER + k0 + cc * 8;
        char* l = (char*)As + (it * 256 + wv * 64) * 16 + lane * 16;
        gload_lds16(g, l);
    }
#pragma unroll
    for (int it = 0; it < 4; ++it) {
        int chunk = it * 256 + tid;
        int cc = (chunk & 7) ^ ((chunk >> 3) & 7);
        const unsigned short* g = B + (size_t)(chunk >> 3) * D_INNER + k0 + cc * 8;
        char* l = (char*)Bs + (it * 256 + wv * 64) * 16 + lane * 16;
        gload_lds16(g, l);
    }
    __syncthreads();
#pragma unroll
    for (int h = 0; h < 2; ++h) {
        bf16x8 af[MI], bfr[NJ];
#pragma unroll
        for (int i = 0; i < MI; ++i)
            af[i] = *(const bf16x8*)(As + (wr * 64 + i * 16 + lm) * 64 + (((h << 2) + q) ^ sw) * 8);
#pragma unroll
        for (int j = 0; j < NJ; ++j)
            bfr[j] = *(const bf16x8*)(Bs + (wc * 64 + j * 16 + lm) * 64 + (((h << 2) + q) ^ sw) * 8);
#pragma unroll
        for (int i = 0; i < MI; ++i)
#pragma unroll
            for (int j = 0; j < NJ; ++j)
                acc[i][j] = __builtin_amdgcn_mfma_f32_16x16x32_bf16(af[i], bfr[j], acc[i][j], 0, 0, 0);
    }
    unsigned short* dst = part + (size_t)blockIdx.y * (NTOK * XPROJ_LD);
#pragma unroll
    for (int i = 0; i < MI; ++i)
#pragma unroll
        for (int j = 0; j < NJ; ++j)
#pragma unroll
            for (int r = 0; r < 4; ++r) {
                int row = m0 + wr * 64 + i * 16 + q * 4 + r;
                int col = wc * 64 + j * 16 + lm;
                dst[(size_t)row * XPROJ_LD + col] = (unsigned short)f2bf_u(acc[i][j][r]);
            }
}

// ---------------- reduce split-K partials (4 elems/thread); emit dbc f32 + dt_raw bf16 ----------------
__global__ __launch_bounds__(256) void k_xred(const unsigned short* __restrict__ part,
                                              float* __restrict__ dbc,
                                              unsigned short* __restrict__ dtrawb) {
    int idx4 = blockIdx.x * 256 + threadIdx.x;  // unit of 4 elems
    float s0 = 0.f, s1 = 0.f, s2 = 0.f, s3 = 0.f;
#pragma unroll
    for (int sp = 0; sp < NSPLIT; ++sp) {
        uint2 v = *(const uint2*)(part + (size_t)sp * (NTOK * XPROJ_LD) + idx4 * 4);
        s0 += __uint_as_float(v.x << 16);
        s1 += __uint_as_float(v.x & 0xFFFF0000u);
        s2 += __uint_as_float(v.y << 16);
        s3 += __uint_as_float(v.y & 0xFFFF0000u);
    }
    float4 sv = {s0, s1, s2, s3};
    *(float4*)(dbc + idx4 * 4) = sv;
    int col = (idx4 * 4) & (XPROJ_LD - 1);
    if (col < DT_RANK) {
        int row = (idx4 * 4) >> 7;
        uint2 o;
        o.x = f2bf_u(s0) | (f2bf_u(s1) << 16);
        o.y = f2bf_u(s2) | (f2bf_u(s3) << 16);
        *(uint2*)(dtrawb + (size_t)row * DT_RANK + col) = o;
    }
}

// ---------------- depthwise causal conv (k=4, bf16 in) + SiLU -> ub ----------------
__global__ __launch_bounds__(256) void k_conv(const unsigned short* __restrict__ xz,
                                              const float* __restrict__ cw,
                                              const float* __restrict__ cb,
                                              unsigned short* __restrict__ ub) {
    int idx = blockIdx.x * 256 + threadIdx.x;
    int c = idx & (D_INNER - 1);
    int t = (idx >> 11) & (T_LEN - 1);
    int b = idx >> 21;
    const unsigned short* xs = xz + (size_t)b * T_LEN * 2 * D_INNER + c;
    float4 wv = *(const float4*)(cw + c * 4);
    float s = cb[c];
    if (t >= 3) s = fmaf(bf2f(xs[(size_t)(t - 3) * 2 * D_INNER]), wv.x, s);
    if (t >= 2) s = fmaf(bf2f(xs[(size_t)(t - 2) * 2 * D_INNER]), wv.y, s);
    if (t >= 1) s = fmaf(bf2f(xs[(size_t)(t - 1) * 2 * D_INNER]), wv.z, s);
    s = fmaf(bf2f(xs[(size_t)t * 2 * D_INNER]), wv.w, s);
    float v = s * sigmoidf_(s);
    ub[idx] = (unsigned short)f2bf_u(v);
}

// ---------------- chunked selective scan, lane-per-channel (3 kernels, proven) ----------------
__global__ __launch_bounds__(256) void k_scan1(const unsigned short* __restrict__ delta,
                                               const unsigned short* __restrict__ ub,
                                               const float* __restrict__ dbc,
                                               const float* __restrict__ A_log,
                                               float* __restrict__ Pbuf,
                                               float* __restrict__ Hbuf) {
    int tid = threadIdx.x;
    int c = blockIdx.x * 256 + tid;
    int b = blockIdx.y >> 5, chunk = blockIdx.y & 31;
    int t0 = chunk * CHUNK_L;
    __shared__ float bc[CHUNK_L][32];  // [t][0:16]=B, [t][16:32]=C
    {
        int t = tid >> 3, col = (tid & 7) * 4;
        const float* src = dbc + ((size_t)b * T_LEN + t0 + t) * XPROJ_LD + DT_RANK + col;
        *(float4*)&bc[t][col] = *(const float4*)src;
    }
    __syncthreads();
    float A[16];
#pragma unroll
    for (int s4 = 0; s4 < 4; ++s4) {
        float4 av = *(const float4*)(A_log + (size_t)c * D_STATE + s4 * 4);
        A[s4 * 4 + 0] = -__expf(av.x);
        A[s4 * 4 + 1] = -__expf(av.y);
        A[s4 * 4 + 2] = -__expf(av.z);
        A[s4 * 4 + 3] = -__expf(av.w);
    }
    const unsigned short* dp = delta + ((size_t)b * T_LEN + t0) * D_INNER + c;
    const unsigned short* up = ub + ((size_t)b * T_LEN + t0) * D_INNER + c;
    float h[16] = {};
    float sumd = 0.f;
#pragma unroll 4
    for (int t = 0; t < CHUNK_L; ++t) {
        float dv = bf2f(dp[(size_t)t * D_INNER]);
        float uv = bf2f(up[(size_t)t * D_INNER]);
        float du = dv * uv;
        sumd += dv;
#pragma unroll
        for (int s = 0; s < 16; ++s) {
            float da = __expf(dv * A[s]);
            h[s] = fmaf(da, h[s], du * bc[t][s]);
        }
    }
    size_t o = ((size_t)((b * NCHUNK + chunk) * D_INNER) + c) * 16;
#pragma unroll
    for (int s4 = 0; s4 < 4; ++s4) {
        float4 hv = {h[s4 * 4], h[s4 * 4 + 1], h[s4 * 4 + 2], h[s4 * 4 + 3]};
        *(float4*)(Hbuf + o + s4 * 4) = hv;
        float4 pv = {__expf(A[s4 * 4] * sumd), __expf(A[s4 * 4 + 1] * sumd),
                     __expf(A[s4 * 4 + 2] * sumd), __expf(A[s4 * 4 + 3] * sumd)};
        *(float4*)(Pbuf + o + s4 * 4) = pv;
    }
}

__global__ __launch_bounds__(256) void k_scan2(const float* __restrict__ Pbuf,
                                               const float* __restrict__ Hbuf,
                                               float* __restrict__ Sbuf) {
    int idx = blockIdx.x * 256 + threadIdx.x;  // 0..65535 = (b, c*16+s)
    int b = idx >> 15, r = idx & 32767;
    size_t base = (size_t)b * NCHUNK * (D_INNER * 16) + r;
    float p[NCHUNK], hl[NCHUNK];
#pragma unroll
    for (int ch = 0; ch < NCHUNK; ++ch) {
        size_t o = base + (size_t)ch * (D_INNER * 16);
        p[ch] = Pbuf[o];
        hl[ch] = Hbuf[o];
    }
    float h = 0.f;
#pragma unroll
    for (int ch = 0; ch < NCHUNK; ++ch) {
        Sbuf[base + (size_t)ch * (D_INNER * 16)] = h;
        h = fmaf(p[ch], h, hl[ch]);
    }
}

__global__ __launch_bounds__(256) void k_scan3(const unsigned short* __restrict__ delta,
                                               const unsigned short* __restrict__ ub,
                                               const float* __restrict__ dbc,
                                               const unsigned short* __restrict__ xz,  // z-half pre-silu'd
                                               const float* __restrict__ A_log,
                                               const float* __restrict__ Dp,
                                               const float* __restrict__ Sbuf,
                                               unsigned short* __restrict__ yb) {
    int tid = threadIdx.x;
    int c = blockIdx.x * 256 + tid;
    int b = blockIdx.y >> 5, chunk = blockIdx.y & 31;
    int t0 = chunk * CHUNK_L;
    __shared__ float bc[CHUNK_L][32];
    {
        int t = tid >> 3, col = (tid & 7) * 4;
        const float* src = dbc + ((size_t)b * T_LEN + t0 + t) * XPROJ_LD + DT_RANK + col;
        *(float4*)&bc[t][col] = *(const float4*)src;
    }
    __syncthreads();
    float A[16];
#pragma unroll
    for (int s4 = 0; s4 < 4; ++s4) {
        float4 av = *(const float4*)(A_log + (size_t)c * D_STATE + s4 * 4);
        A[s4 * 4 + 0] = -__expf(av.x);
        A[s4 * 4 + 1] = -__expf(av.y);
        A[s4 * 4 + 2] = -__expf(av.z);
        A[s4 * 4 + 3] = -__expf(av.w);
    }
    float Dc = Dp[c];
    float h[16];
    size_t ho = ((size_t)((b * NCHUNK + chunk) * D_INNER) + c) * 16;
#pragma unroll
    for (int s4 = 0; s4 < 4; ++s4) {
        float4 hv = *(const float4*)(Sbuf + ho + s4 * 4);
        h[s4 * 4] = hv.x; h[s4 * 4 + 1] = hv.y; h[s4 * 4 + 2] = hv.z; h[s4 * 4 + 3] = hv.w;
    }
    const unsigned short* dp = delta + ((size_t)b * T_LEN + t0) * D_INNER + c;
    const unsigned short* up = ub + ((size_t)b * T_LEN + t0) * D_INNER + c;
    const unsigned short* zp = xz + ((size_t)b * T_LEN + t0) * 2 * D_INNER + D_INNER + c;
    unsigned short* yp = yb + ((size_t)b * T_LEN + t0) * D_INNER + c;
#pragma unroll 2
    for (int t = 0; t < CHUNK_L; ++t) {
        float dv = bf2f(dp[(size_t)t * D_INNER]);
        float uv = bf2f(up[(size_t)t * D_INNER]);
        float sz = bf2f(zp[(size_t)t * 2 * D_INNER]);  // already silu(z)
        float du = dv * uv;
        float y = Dc * uv;
#pragma unroll
        for (int s = 0; s < 16; ++s) {
            float da = __expf(dv * A[s]);
            h[s] = fmaf(da, h[s], du * bc[t][s]);
            y = fmaf(h[s], bc[t][16 + s], y);
        }
        yp[(size_t)t * D_INNER] = (unsigned short)f2bf_u(y * sz);
    }
}

extern "C" void kernel_launch(void* const* d_in, const int* in_sizes, int n_in,
                              void* d_out, int out_size, void* d_ws, size_t ws_size,
                              hipStream_t stream) {
    const float* x         = (const float*)d_in[0];
    const float* norm_w    = (const float*)d_in[1];
    const float* in_proj_w = (const float*)d_in[2];
    const float* conv_w    = (const float*)d_in[3];
    const float* conv_b    = (const float*)d_in[4];
    const float* x_proj_w  = (const float*)d_in[5];
    const float* dt_proj_w = (const float*)d_in[6];
    const float* dt_proj_b = (const float*)d_in[7];
    const float* A_log     = (const float*)d_in[8];
    const float* D_param   = (const float*)d_in[9];
    const float* out_proj_w= (const float*)d_in[10];
    float* out = (float*)d_out;

    // workspace layout (float units), flat; total 25,690,112 floats = 102.8 MB
    float* ws = (float*)d_ws;
    unsigned short* xzb    = (unsigned short*)(ws);            // 2048*4096 bf16 (z-half silu'd)
    unsigned short* ub     = (unsigned short*)(ws + 4194304);  // 2048*2048 bf16
    unsigned short* yb     = (unsigned short*)(ws + 6291456);  // 2048*2048 bf16
    unsigned short* partb  = (unsigned short*)(ws + 8388608);  // 32*2048*128 bf16
    float*          dbc    = ws + 12582912;                    // 2048*128 f32
    unsigned short* deltab = (unsigned short*)(ws + 12845056); // 2048*2048 bf16
    float*          Pbuf   = ws + 14942208;                    // 2*32*2048*16 f32
    float*          Hbuf   = ws + 17039360;                    // 2*32*2048*16 f32
    float*          Sbuf   = ws + 19136512;                    // 2*32*2048*16 f32
    unsigned short* wib    = (unsigned short*)(ws + 21233664); // 4096*1024 bf16
    unsigned short* wob    = (unsigned short*)(ws + 23330816); // 1024*2048 bf16
    unsigned short* wxb    = (unsigned short*)(ws + 24379392); // 128*2048 bf16
    unsigned short* wdtb   = (unsigned short*)(ws + 24510464); // 2048*64 bf16
    unsigned short* dtrawb = (unsigned short*)(ws + 24576000); // 2048*64 bf16
    unsigned short* xnb    = (unsigned short*)(ws + 24641536); // 2048*1024 bf16

    // 0. fused RMSNorm + all weight casts (one launch)
    k_prep<<<5312, 256, 0, stream>>>(x, norm_w, in_proj_w, out_proj_w, x_proj_w, dt_proj_w,
                                     xnb, (unsigned*)wib, (unsigned*)wob, (unsigned*)wxb,
                                     (unsigned*)wdtb);
    // 1. xz = xn @ in_proj_w^T (2048x4096x1024) -> bf16; z-half fused silu (512 blocks)
    gemm_bf16<128, 2, 3><<<dim3(NTOK / 128, 4096 / 128), 256, 0, stream>>>(
        xnb, wib, xzb, 2 * D_INNER, D_MODEL, nullptr);
    // 2. depthwise conv + SiLU -> ub
    k_conv<<<(NTOK * D_INNER) / 256, 256, 0, stream>>>(xzb, conv_w, conv_b, ub);
    // 3. x_dbc: split-K MFMA GEMM (32 slabs of K=64, 512 blocks) + reduce
    xproj_gemm<<<dim3(NTOK / 128, NSPLIT), 256, 0, stream>>>(ub, wxb, partb);
    k_xred<<<(NTOK * XPROJ_LD) / 1024, 256, 0, stream>>>(partb, dbc, dtrawb);
    // 4. delta = softplus(dt_raw @ dt_proj_w^T + b) -> bf16 (BN=64: 512 blocks)
    gemm_bf16<64, 1, 1><<<dim3(NTOK / 128, D_INNER / 64), 256, 0, stream>>>(
        dtrawb, wdtb, deltab, D_INNER, DT_RANK, dt_proj_b);
    // 5. chunked selective scan (3 kernels) -> yb
    k_scan1<<<dim3(D_INNER / 256, B_SZ * NCHUNK), 256, 0, stream>>>(deltab, ub, dbc, A_log,
                                                                    Pbuf, Hbuf);
    k_scan2<<<(B_SZ * D_INNER * D_STATE) / 256, 256, 0, stream>>>(Pbuf, Hbuf, Sbuf);
    k_scan3<<<dim3(D_INNER / 256, B_SZ * NCHUNK), 256, 0, stream>>>(deltab, ub, dbc, xzb, A_log,
                                                                    D_param, Sbuf, yb);
    // 6. out = y @ out_proj_w^T + x (2048x1024x2048), 64x64 tiles (512 blocks)
    gemm_sq64<<<dim3(NTOK / 64, D_MODEL / 64), 256, 0, stream>>>(
        yb, wob, out, D_MODEL, D_INNER, x);

    (void)in_sizes; (void)n_in; (void)out_size; (void)ws_size;
}